// Round 1
// baseline (987.001 us; speedup 1.0000x reference)
//
#include <hip/hip_runtime.h>
#include <math.h>

#define N_NODES 50000
#define N_EDGES 800000
#define E_TOT   (N_EDGES + N_NODES)   // 850000, every node has >=1 in-edge (self-loop)
#define HEADS   4
#define NEG     0.2f

// ---------------- CSR build (dst-sorted) ----------------

__global__ void count_deg(const int* __restrict__ edst, int* __restrict__ cnt) {
    int i = blockIdx.x * blockDim.x + threadIdx.x;
    if (i >= E_TOT) return;
    int d = (i < N_EDGES) ? edst[i] : (i - N_EDGES);
    atomicAdd(&cnt[d], 1);
}

// single block, 1024 threads: exclusive scan of cnt[0..N) into off[0..N]
__global__ void scan_block(const int* __restrict__ cnt, int* __restrict__ off) {
    __shared__ int sums[1024];
    int tid = threadIdx.x;
    const int chunk = (N_NODES + 1023) / 1024;   // 49
    int start = tid * chunk;
    int end = min(start + chunk, N_NODES);
    int s = 0;
    for (int i = start; i < end; ++i) s += cnt[i];
    sums[tid] = s;
    __syncthreads();
    int local = s;
    for (int d = 1; d < 1024; d <<= 1) {
        int add = (tid >= d) ? sums[tid - d] : 0;
        __syncthreads();
        sums[tid] += add;
        __syncthreads();
    }
    int run = sums[tid] - local;   // exclusive prefix
    for (int i = start; i < end; ++i) { off[i] = run; run += cnt[i]; }
    if (tid == 0) off[N_NODES] = E_TOT;
}

__global__ void scatter_edges(const int* __restrict__ esrc, const int* __restrict__ edst,
                              int* __restrict__ cursor, int* __restrict__ csr_src) {
    int i = blockIdx.x * blockDim.x + threadIdx.x;
    if (i >= E_TOT) return;
    int s, d;
    if (i < N_EDGES) { s = esrc[i]; d = edst[i]; }
    else             { s = i - N_EDGES; d = s; }
    int pos = atomicAdd(&cursor[d], 1);
    csr_src[pos] = s;
}

// ---------------- fp32 GEMM: C[n,m] = X[n,k] @ W[m,k]^T (+bias) ----------------

__global__ __launch_bounds__(256) void gemm_xwt(
        const float* __restrict__ X, const float* __restrict__ W,
        const float* __restrict__ bias, float* __restrict__ C,
        int n, int k, int m) {
    __shared__ float As[16][65];   // [kk][row]
    __shared__ float Bs[16][65];   // [kk][col]
    int tid = threadIdx.x;
    int tx = tid & 15, ty = tid >> 4;
    int r0 = blockIdx.y * 64, c0 = blockIdx.x * 64;
    float acc[4][4] = {};
    for (int kt = 0; kt < k; kt += 16) {
        #pragma unroll
        for (int l = 0; l < 4; ++l) {
            int idx = l * 256 + tid;
            int row = idx >> 4, kk = idx & 15;
            int gk = kt + kk;
            float v = 0.f;
            int gr = r0 + row;
            if (gr < n && gk < k) v = X[(size_t)gr * k + gk];
            As[kk][row] = v;
            float wv = 0.f;
            int gc = c0 + row;
            if (gc < m && gk < k) wv = W[(size_t)gc * k + gk];
            Bs[kk][row] = wv;
        }
        __syncthreads();
        #pragma unroll
        for (int kk = 0; kk < 16; ++kk) {
            float a[4], b[4];
            #pragma unroll
            for (int i = 0; i < 4; ++i) a[i] = As[kk][ty * 4 + i];
            #pragma unroll
            for (int j = 0; j < 4; ++j) b[j] = Bs[kk][tx * 4 + j];
            #pragma unroll
            for (int i = 0; i < 4; ++i)
                #pragma unroll
                for (int j = 0; j < 4; ++j)
                    acc[i][j] += a[i] * b[j];
        }
        __syncthreads();
    }
    #pragma unroll
    for (int i = 0; i < 4; ++i) {
        int gr = r0 + ty * 4 + i;
        if (gr >= n) continue;
        #pragma unroll
        for (int j = 0; j < 4; ++j) {
            int gc = c0 + tx * 4 + j;
            if (gc >= m) continue;
            float v = acc[i][j];
            if (bias) v += bias[gc];
            C[(size_t)gr * m + gc] = v;
        }
    }
}

// ---------------- per-(node,head) attention logits ----------------

__global__ void calc_alpha(const float* __restrict__ HF,
                           const float* __restrict__ a_src, const float* __restrict__ a_dst,
                           float* __restrict__ asrc, float* __restrict__ adst,
                           int C, int stride) {
    int t = blockIdx.x * blockDim.x + threadIdx.x;   // n*HEADS + h
    if (t >= N_NODES * HEADS) return;
    int n = t >> 2, h = t & 3;
    const float* row = HF + (size_t)n * stride + h * C;
    const float* as = a_src + h * C;
    const float* ad = a_dst + h * C;
    float ss = 0.f, sd = 0.f;
    for (int c = 0; c < C; ++c) { float v = row[c]; ss += v * as[c]; sd += v * ad[c]; }
    asrc[t] = ss; adst[t] = sd;
}

// ---------------- aggregation layers 1-2 (F = H*HID = 128, concat, +lin, relu) ----------------

__global__ __launch_bounds__(256) void agg12(
        const int* __restrict__ off, const int* __restrict__ csr_src,
        const float* __restrict__ HF, const float* __restrict__ asrc,
        const float* __restrict__ adst, const float* __restrict__ bias,
        const float* __restrict__ LIN, float* __restrict__ OUT) {
    int wv = threadIdx.x >> 6, lane = threadIdx.x & 63;
    int n = blockIdx.x * 4 + wv;                     // grid is exact: 50000/4
    int e0 = off[n], e1 = off[n + 1];
    int h0 = lane >> 5, h1 = 2 + (lane >> 5);
    float adv0 = adst[n * 4 + 0], adv1 = adst[n * 4 + 1];
    float adv2 = adst[n * 4 + 2], adv3 = adst[n * 4 + 3];
    // phase A: per-head max over incoming edges (edge-parallel across lanes)
    float mx0 = -INFINITY, mx1 = -INFINITY, mx2 = -INFINITY, mx3 = -INFINITY;
    for (int e = e0 + lane; e < e1; e += 64) {
        int s = csr_src[e];
        float v;
        v = asrc[s * 4 + 0] + adv0; v = v > 0.f ? v : NEG * v; mx0 = fmaxf(mx0, v);
        v = asrc[s * 4 + 1] + adv1; v = v > 0.f ? v : NEG * v; mx1 = fmaxf(mx1, v);
        v = asrc[s * 4 + 2] + adv2; v = v > 0.f ? v : NEG * v; mx2 = fmaxf(mx2, v);
        v = asrc[s * 4 + 3] + adv3; v = v > 0.f ? v : NEG * v; mx3 = fmaxf(mx3, v);
    }
    #pragma unroll
    for (int d = 32; d; d >>= 1) {
        mx0 = fmaxf(mx0, __shfl_xor(mx0, d));
        mx1 = fmaxf(mx1, __shfl_xor(mx1, d));
        mx2 = fmaxf(mx2, __shfl_xor(mx2, d));
        mx3 = fmaxf(mx3, __shfl_xor(mx3, d));
    }
    float m0 = (h0 == 0) ? mx0 : mx1;         // head for feature f0 = lane
    float m1 = (h0 == 0) ? mx2 : mx3;         // head for feature f1 = lane+64
    float ad0 = (h0 == 0) ? adv0 : adv1;
    float ad1 = (h0 == 0) ? adv2 : adv3;
    // phase B: edge-serial, lanes over 128 features
    float acc0 = 0.f, acc1 = 0.f, den0 = 0.f, den1 = 0.f;
    for (int e = e0; e < e1; ++e) {
        int s = csr_src[e];
        float v0 = asrc[s * 4 + h0] + ad0; v0 = v0 > 0.f ? v0 : NEG * v0;
        float v1 = asrc[s * 4 + h1] + ad1; v1 = v1 > 0.f ? v1 : NEG * v1;
        float w0 = __expf(v0 - m0);
        float w1 = __expf(v1 - m1);
        const float* hr = HF + (size_t)s * 128;
        acc0 += w0 * hr[lane];
        acc1 += w1 * hr[lane + 64];
        den0 += w0; den1 += w1;
    }
    size_t base = (size_t)n * 128;
    float o0 = acc0 / (den0 + 1e-16f) + bias[lane]      + LIN[base + lane];
    float o1 = acc1 / (den1 + 1e-16f) + bias[lane + 64] + LIN[base + lane + 64];
    OUT[base + lane]      = fmaxf(o0, 0.f);
    OUT[base + lane + 64] = fmaxf(o1, 0.f);
}

// ---------------- layer 3: aggregate (188), mean heads (47), +lin, log_softmax ----------------

__global__ __launch_bounds__(256) void agg3(
        const int* __restrict__ off, const int* __restrict__ csr_src,
        const float* __restrict__ HF, const float* __restrict__ asrc,
        const float* __restrict__ adst, const float* __restrict__ b3,
        const float* __restrict__ LIN, float* __restrict__ OUT) {
    __shared__ float tbuf[4][188];
    int wv = threadIdx.x >> 6, lane = threadIdx.x & 63;
    int n = blockIdx.x * 4 + wv;                     // exact grid
    int e0 = off[n], e1 = off[n + 1];
    float adv[4];
    #pragma unroll
    for (int h = 0; h < 4; ++h) adv[h] = adst[n * 4 + h];
    float mx[4] = {-INFINITY, -INFINITY, -INFINITY, -INFINITY};
    for (int e = e0 + lane; e < e1; e += 64) {
        int s = csr_src[e];
        #pragma unroll
        for (int h = 0; h < 4; ++h) {
            float v = asrc[s * 4 + h] + adv[h];
            v = v > 0.f ? v : NEG * v;
            mx[h] = fmaxf(mx[h], v);
        }
    }
    #pragma unroll
    for (int d = 32; d; d >>= 1)
        #pragma unroll
        for (int h = 0; h < 4; ++h) mx[h] = fmaxf(mx[h], __shfl_xor(mx[h], d));

    int f0 = lane, f1 = lane + 64, f2 = lane + 128;
    int h0 = f0 / 47, h1 = f1 / 47;
    int h2 = (f2 < 188) ? (f2 / 47) : 3;
    float acc0 = 0.f, acc1 = 0.f, acc2 = 0.f;
    float den[4] = {0.f, 0.f, 0.f, 0.f};
    for (int e = e0; e < e1; ++e) {
        int s = csr_src[e];
        float w[4];
        #pragma unroll
        for (int h = 0; h < 4; ++h) {
            float v = asrc[s * 4 + h] + adv[h];
            v = v > 0.f ? v : NEG * v;
            w[h] = __expf(v - mx[h]);
            den[h] += w[h];
        }
        const float* hr = HF + (size_t)s * 188;
        acc0 += w[h0] * hr[f0];
        acc1 += w[h1] * hr[f1];
        if (f2 < 188) acc2 += w[h2] * hr[f2];
    }
    tbuf[wv][f0] = acc0 / (den[h0] + 1e-16f);
    tbuf[wv][f1] = acc1 / (den[h1] + 1e-16f);
    if (f2 < 188) tbuf[wv][f2] = acc2 / (den[h2] + 1e-16f);
    __syncthreads();
    float z = -INFINITY;
    if (lane < 47) {
        z = 0.25f * (tbuf[wv][lane] + tbuf[wv][47 + lane] + tbuf[wv][94 + lane] + tbuf[wv][141 + lane])
            + b3[lane] + LIN[(size_t)n * 47 + lane];
    }
    float m = z;
    #pragma unroll
    for (int d = 32; d; d >>= 1) m = fmaxf(m, __shfl_xor(m, d));
    float ex = (lane < 47) ? __expf(z - m) : 0.f;
    float ssum = ex;
    #pragma unroll
    for (int d = 32; d; d >>= 1) ssum += __shfl_xor(ssum, d);
    if (lane < 47) OUT[(size_t)n * 47 + lane] = z - m - logf(ssum);
}

// ---------------- launch ----------------

extern "C" void kernel_launch(void* const* d_in, const int* in_sizes, int n_in,
                              void* d_out, int out_size, void* d_ws, size_t ws_size,
                              hipStream_t stream) {
    const float* x   = (const float*)d_in[0];
    const int*   ei  = (const int*)d_in[1];
    const float* W1  = (const float*)d_in[2];
    const float* a1s = (const float*)d_in[3];
    const float* a1d = (const float*)d_in[4];
    const float* b1  = (const float*)d_in[5];
    const float* Wl1 = (const float*)d_in[6];
    const float* bl1 = (const float*)d_in[7];
    const float* W2  = (const float*)d_in[8];
    const float* a2s = (const float*)d_in[9];
    const float* a2d = (const float*)d_in[10];
    const float* b2  = (const float*)d_in[11];
    const float* Wl2 = (const float*)d_in[12];
    const float* bl2 = (const float*)d_in[13];
    const float* W3  = (const float*)d_in[14];
    const float* a3s = (const float*)d_in[15];
    const float* a3d = (const float*)d_in[16];
    const float* b3  = (const float*)d_in[17];
    const float* Wl3 = (const float*)d_in[18];
    const float* bl3 = (const float*)d_in[19];
    float* out = (float*)d_out;

    size_t cur = 0;
    char* wsb = (char*)d_ws;
    auto carve = [&](size_t bytes) -> void* {
        void* p = wsb + cur;
        cur += (bytes + 255) & ~(size_t)255;
        return p;
    };
    int*   cnt    = (int*)  carve((size_t)N_NODES * 4);
    int*   offs   = (int*)  carve((size_t)(N_NODES + 1) * 4);
    int*   cursor = (int*)  carve((size_t)N_NODES * 4);
    int*   csr    = (int*)  carve((size_t)E_TOT * 4);
    float* HF     = (float*)carve((size_t)N_NODES * 188 * 4);
    float* LIN    = (float*)carve((size_t)N_NODES * 128 * 4);
    float* ASRC   = (float*)carve((size_t)N_NODES * 4 * 4);
    float* ADST   = (float*)carve((size_t)N_NODES * 4 * 4);
    float* B      = (float*)carve((size_t)N_NODES * 128 * 4);

    const int* esrc = ei;
    const int* edst = ei + N_EDGES;

    // CSR build (once per launch; edges fixed)
    hipMemsetAsync(cnt, 0, (size_t)N_NODES * 4, stream);
    int egrid = (E_TOT + 255) / 256;
    count_deg<<<egrid, 256, 0, stream>>>(edst, cnt);
    scan_block<<<1, 1024, 0, stream>>>(cnt, offs);
    hipMemcpyAsync(cursor, offs, (size_t)N_NODES * 4, hipMemcpyDeviceToDevice, stream);
    scatter_edges<<<egrid, 256, 0, stream>>>(esrc, edst, cursor, csr);

    int agrid = (N_NODES * HEADS + 255) / 256;
    int ngrid = N_NODES / 4;   // 12500, exact

    // ---- layer 1 ----
    {
        dim3 g((128 + 63) / 64, (N_NODES + 63) / 64);
        gemm_xwt<<<g, 256, 0, stream>>>(x, W1, nullptr, HF, N_NODES, 100, 128);
        gemm_xwt<<<g, 256, 0, stream>>>(x, Wl1, bl1, LIN, N_NODES, 100, 128);
        calc_alpha<<<agrid, 256, 0, stream>>>(HF, a1s, a1d, ASRC, ADST, 32, 128);
        agg12<<<ngrid, 256, 0, stream>>>(offs, csr, HF, ASRC, ADST, b1, LIN, B);
    }
    // ---- layer 2 ----
    {
        dim3 g((128 + 63) / 64, (N_NODES + 63) / 64);
        gemm_xwt<<<g, 256, 0, stream>>>(B, W2, nullptr, HF, N_NODES, 128, 128);
        gemm_xwt<<<g, 256, 0, stream>>>(B, Wl2, bl2, LIN, N_NODES, 128, 128);
        calc_alpha<<<agrid, 256, 0, stream>>>(HF, a2s, a2d, ASRC, ADST, 32, 128);
        agg12<<<ngrid, 256, 0, stream>>>(offs, csr, HF, ASRC, ADST, b2, LIN, B);
    }
    // ---- layer 3 ----
    {
        dim3 g3a((188 + 63) / 64, (N_NODES + 63) / 64);
        gemm_xwt<<<g3a, 256, 0, stream>>>(B, W3, nullptr, HF, N_NODES, 128, 188);
        dim3 g3b((47 + 63) / 64, (N_NODES + 63) / 64);
        gemm_xwt<<<g3b, 256, 0, stream>>>(B, Wl3, bl3, LIN, N_NODES, 128, 47);
        calc_alpha<<<agrid, 256, 0, stream>>>(HF, a3s, a3d, ASRC, ADST, 47, 188);
        agg3<<<ngrid, 256, 0, stream>>>(offs, csr, HF, ASRC, ADST, b3, LIN, out);
    }
}

// Round 2
// 969.192 us; speedup vs baseline: 1.0184x; 1.0184x over previous
//
#include <hip/hip_runtime.h>
#include <hip/hip_bf16.h>
#include <math.h>

#define N_NODES 50000
#define N_EDGES 800000
#define E_TOT   (N_EDGES + N_NODES)   // 850000
#define HEADS   4
#define NEG     0.2f

__device__ __forceinline__ float bf_lo(unsigned u) { return __uint_as_float(u << 16); }
__device__ __forceinline__ float bf_hi(unsigned u) { return __uint_as_float(u & 0xffff0000u); }

// ---------------- CSR build (dst-sorted) ----------------

__global__ void count_deg(const int* __restrict__ edst, int* __restrict__ cnt) {
    int i = blockIdx.x * blockDim.x + threadIdx.x;
    if (i >= E_TOT) return;
    int d = (i < N_EDGES) ? edst[i] : (i - N_EDGES);
    atomicAdd(&cnt[d], 1);
}

__global__ void scan_block(const int* __restrict__ cnt, int* __restrict__ off) {
    __shared__ int sums[1024];
    int tid = threadIdx.x;
    const int chunk = (N_NODES + 1023) / 1024;
    int start = tid * chunk;
    int end = min(start + chunk, N_NODES);
    int s = 0;
    for (int i = start; i < end; ++i) s += cnt[i];
    sums[tid] = s;
    __syncthreads();
    int local = s;
    for (int d = 1; d < 1024; d <<= 1) {
        int add = (tid >= d) ? sums[tid - d] : 0;
        __syncthreads();
        sums[tid] += add;
        __syncthreads();
    }
    int run = sums[tid] - local;
    for (int i = start; i < end; ++i) { off[i] = run; run += cnt[i]; }
    if (tid == 0) off[N_NODES] = E_TOT;
}

__global__ void scatter_edges(const int* __restrict__ esrc, const int* __restrict__ edst,
                              int* __restrict__ cursor, int* __restrict__ csr_src) {
    int i = blockIdx.x * blockDim.x + threadIdx.x;
    if (i >= E_TOT) return;
    int s, d;
    if (i < N_EDGES) { s = esrc[i]; d = edst[i]; }
    else             { s = i - N_EDGES; d = s; }
    int pos = atomicAdd(&cursor[d], 1);
    csr_src[pos] = s;
}

// ---------------- fp32 GEMM: C = X @ W^T (+bias), optional bf16 mirror ----------------

__global__ __launch_bounds__(256) void gemm_xwt(
        const float* __restrict__ X, const float* __restrict__ W,
        const float* __restrict__ bias, float* __restrict__ C,
        __hip_bfloat16* __restrict__ Cb,
        int n, int k, int m) {
    __shared__ float As[16][65];
    __shared__ float Bs[16][65];
    int tid = threadIdx.x;
    int tx = tid & 15, ty = tid >> 4;
    int r0 = blockIdx.y * 64, c0 = blockIdx.x * 64;
    float acc[4][4] = {};
    for (int kt = 0; kt < k; kt += 16) {
        #pragma unroll
        for (int l = 0; l < 4; ++l) {
            int idx = l * 256 + tid;
            int row = idx >> 4, kk = idx & 15;
            int gk = kt + kk;
            float v = 0.f;
            int gr = r0 + row;
            if (gr < n && gk < k) v = X[(size_t)gr * k + gk];
            As[kk][row] = v;
            float wv = 0.f;
            int gc = c0 + row;
            if (gc < m && gk < k) wv = W[(size_t)gc * k + gk];
            Bs[kk][row] = wv;
        }
        __syncthreads();
        #pragma unroll
        for (int kk = 0; kk < 16; ++kk) {
            float a[4], b[4];
            #pragma unroll
            for (int i = 0; i < 4; ++i) a[i] = As[kk][ty * 4 + i];
            #pragma unroll
            for (int j = 0; j < 4; ++j) b[j] = Bs[kk][tx * 4 + j];
            #pragma unroll
            for (int i = 0; i < 4; ++i)
                #pragma unroll
                for (int j = 0; j < 4; ++j)
                    acc[i][j] += a[i] * b[j];
        }
        __syncthreads();
    }
    #pragma unroll
    for (int i = 0; i < 4; ++i) {
        int gr = r0 + ty * 4 + i;
        if (gr >= n) continue;
        #pragma unroll
        for (int j = 0; j < 4; ++j) {
            int gc = c0 + tx * 4 + j;
            if (gc >= m) continue;
            float v = acc[i][j];
            if (bias) v += bias[gc];
            C[(size_t)gr * m + gc] = v;
            if (Cb) Cb[(size_t)gr * m + gc] = __float2bfloat16(v);
        }
    }
}

// ---------------- per-(node,head) attention logits (fp32 HF) ----------------

__global__ void calc_alpha(const float* __restrict__ HF,
                           const float* __restrict__ a_src, const float* __restrict__ a_dst,
                           float* __restrict__ asrc, float* __restrict__ adst,
                           int C, int stride) {
    int t = blockIdx.x * blockDim.x + threadIdx.x;
    if (t >= N_NODES * HEADS) return;
    int n = t >> 2, h = t & 3;
    const float* row = HF + (size_t)n * stride + h * C;
    const float* as = a_src + h * C;
    const float* ad = a_dst + h * C;
    float ss = 0.f, sd = 0.f;
    for (int c = 0; c < C; ++c) { float v = row[c]; ss += v * as[c]; sd += v * ad[c]; }
    asrc[t] = ss; adst[t] = sd;
}

// ---------------- aggregation layers 1-2 (bf16 feature gather) ----------------

__global__ __launch_bounds__(256) void agg12(
        const int* __restrict__ off, const int* __restrict__ csr_src,
        const unsigned* __restrict__ HU,   // bf16 HF as uint pairs: [N][64]
        const float* __restrict__ asrc, const float* __restrict__ adst,
        const float* __restrict__ bias, const float* __restrict__ LIN,
        float* __restrict__ OUT) {
    int wv = threadIdx.x >> 6, lane = threadIdx.x & 63;
    int n = blockIdx.x * 4 + wv;
    int e0 = off[n], e1 = off[n + 1];
    int h = lane >> 4;                 // head for features 2l, 2l+1
    float4 advv = ((const float4*)adst)[n];
    float adv[4] = {advv.x, advv.y, advv.z, advv.w};
    // phase A: per-head max over incoming edges
    float mx[4] = {-INFINITY, -INFINITY, -INFINITY, -INFINITY};
    for (int e = e0 + lane; e < e1; e += 64) {
        int s = csr_src[e];
        float4 av = ((const float4*)asrc)[s];
        float a4[4] = {av.x, av.y, av.z, av.w};
        #pragma unroll
        for (int hh = 0; hh < 4; ++hh) {
            float v = a4[hh] + adv[hh];
            v = v > 0.f ? v : NEG * v;
            mx[hh] = fmaxf(mx[hh], v);
        }
    }
    #pragma unroll
    for (int d = 32; d; d >>= 1)
        #pragma unroll
        for (int hh = 0; hh < 4; ++hh) mx[hh] = fmaxf(mx[hh], __shfl_xor(mx[hh], d));
    float mh = mx[h], adh = adv[h];
    // phase B: edge-serial; lane handles features 2l, 2l+1 (same head)
    float acc0 = 0.f, acc1 = 0.f, den = 0.f;
    for (int e = e0; e < e1; ++e) {
        int s = csr_src[e];
        float v = asrc[s * 4 + h] + adh;
        v = v > 0.f ? v : NEG * v;
        float w = __expf(v - mh);
        unsigned u = HU[(size_t)s * 64 + lane];
        acc0 += w * bf_lo(u);
        acc1 += w * bf_hi(u);
        den += w;
    }
    int f0 = 2 * lane, f1 = 2 * lane + 1;
    size_t base = (size_t)n * 128;
    float inv = 1.0f / (den + 1e-16f);
    float o0 = acc0 * inv + bias[f0] + LIN[base + f0];
    float o1 = acc1 * inv + bias[f1] + LIN[base + f1];
    OUT[base + f0] = fmaxf(o0, 0.f);
    OUT[base + f1] = fmaxf(o1, 0.f);
}

// ---------------- layer 3: aggregate (188 bf16), mean heads, +lin, log_softmax ----------------

__global__ __launch_bounds__(256) void agg3(
        const int* __restrict__ off, const int* __restrict__ csr_src,
        const unsigned* __restrict__ HU,   // bf16 HF: [N][94] uints
        const float* __restrict__ asrc, const float* __restrict__ adst,
        const float* __restrict__ b3, const float* __restrict__ LIN,
        float* __restrict__ OUT) {
    __shared__ float tbuf[4][188];
    int wv = threadIdx.x >> 6, lane = threadIdx.x & 63;
    int n = blockIdx.x * 4 + wv;
    int e0 = off[n], e1 = off[n + 1];
    float4 advv = ((const float4*)adst)[n];
    float adv[4] = {advv.x, advv.y, advv.z, advv.w};
    float mx[4] = {-INFINITY, -INFINITY, -INFINITY, -INFINITY};
    for (int e = e0 + lane; e < e1; e += 64) {
        int s = csr_src[e];
        float4 av = ((const float4*)asrc)[s];
        float a4[4] = {av.x, av.y, av.z, av.w};
        #pragma unroll
        for (int hh = 0; hh < 4; ++hh) {
            float v = a4[hh] + adv[hh];
            v = v > 0.f ? v : NEG * v;
            mx[hh] = fmaxf(mx[hh], v);
        }
    }
    #pragma unroll
    for (int d = 32; d; d >>= 1)
        #pragma unroll
        for (int hh = 0; hh < 4; ++hh) mx[hh] = fmaxf(mx[hh], __shfl_xor(mx[hh], d));

    // lane covers features 2l,2l+1 and (if l<30) 128+2l,129+2l
    int f0 = 2 * lane, f1 = 2 * lane + 1;
    int f2 = 128 + 2 * lane, f3 = 129 + 2 * lane;
    bool has2 = (lane < 30);
    int hA = f0 / 47, hB = f1 / 47;
    int hC = has2 ? (f2 / 47) : 3, hD = has2 ? (f3 / 47) : 3;
    float acc0 = 0.f, acc1 = 0.f, acc2 = 0.f, acc3 = 0.f;
    float den[4] = {0.f, 0.f, 0.f, 0.f};
    for (int e = e0; e < e1; ++e) {
        int s = csr_src[e];
        float4 av = ((const float4*)asrc)[s];
        float a4[4] = {av.x, av.y, av.z, av.w};
        float w[4];
        #pragma unroll
        for (int hh = 0; hh < 4; ++hh) {
            float v = a4[hh] + adv[hh];
            v = v > 0.f ? v : NEG * v;
            w[hh] = __expf(v - mx[hh]);
            den[hh] += w[hh];
        }
        const unsigned* row = HU + (size_t)s * 94;
        unsigned u0 = row[lane];
        acc0 += w[hA] * bf_lo(u0);
        acc1 += w[hB] * bf_hi(u0);
        if (has2) {
            unsigned u1 = row[64 + lane];
            acc2 += w[hC] * bf_lo(u1);
            acc3 += w[hD] * bf_hi(u1);
        }
    }
    tbuf[wv][f0] = acc0 / (den[hA] + 1e-16f);
    tbuf[wv][f1] = acc1 / (den[hB] + 1e-16f);
    if (has2) {
        tbuf[wv][f2] = acc2 / (den[hC] + 1e-16f);
        tbuf[wv][f3] = acc3 / (den[hD] + 1e-16f);
    }
    __syncthreads();
    float z = -INFINITY;
    if (lane < 47) {
        z = 0.25f * (tbuf[wv][lane] + tbuf[wv][47 + lane] + tbuf[wv][94 + lane] + tbuf[wv][141 + lane])
            + b3[lane] + LIN[(size_t)n * 47 + lane];
    }
    float m = z;
    #pragma unroll
    for (int d = 32; d; d >>= 1) m = fmaxf(m, __shfl_xor(m, d));
    float ex = (lane < 47) ? __expf(z - m) : 0.f;
    float ssum = ex;
    #pragma unroll
    for (int d = 32; d; d >>= 1) ssum += __shfl_xor(ssum, d);
    if (lane < 47) OUT[(size_t)n * 47 + lane] = z - m - logf(ssum);
}

// ---------------- launch ----------------

extern "C" void kernel_launch(void* const* d_in, const int* in_sizes, int n_in,
                              void* d_out, int out_size, void* d_ws, size_t ws_size,
                              hipStream_t stream) {
    const float* x   = (const float*)d_in[0];
    const int*   ei  = (const int*)d_in[1];
    const float* W1  = (const float*)d_in[2];
    const float* a1s = (const float*)d_in[3];
    const float* a1d = (const float*)d_in[4];
    const float* b1  = (const float*)d_in[5];
    const float* Wl1 = (const float*)d_in[6];
    const float* bl1 = (const float*)d_in[7];
    const float* W2  = (const float*)d_in[8];
    const float* a2s = (const float*)d_in[9];
    const float* a2d = (const float*)d_in[10];
    const float* b2  = (const float*)d_in[11];
    const float* Wl2 = (const float*)d_in[12];
    const float* bl2 = (const float*)d_in[13];
    const float* W3  = (const float*)d_in[14];
    const float* a3s = (const float*)d_in[15];
    const float* a3d = (const float*)d_in[16];
    const float* b3  = (const float*)d_in[17];
    const float* Wl3 = (const float*)d_in[18];
    const float* bl3 = (const float*)d_in[19];
    float* out = (float*)d_out;

    size_t cur = 0;
    char* wsb = (char*)d_ws;
    auto carve = [&](size_t bytes) -> void* {
        void* p = wsb + cur;
        cur += (bytes + 255) & ~(size_t)255;
        return p;
    };
    int*   cnt    = (int*)  carve((size_t)N_NODES * 4);
    int*   offs   = (int*)  carve((size_t)(N_NODES + 1) * 4);
    int*   cursor = (int*)  carve((size_t)N_NODES * 4);
    int*   csr    = (int*)  carve((size_t)E_TOT * 4);
    float* HF     = (float*)carve((size_t)N_NODES * 188 * 4);
    __hip_bfloat16* HFb = (__hip_bfloat16*)carve((size_t)N_NODES * 188 * 2);
    float* LIN    = (float*)carve((size_t)N_NODES * 128 * 4);
    float* ASRC   = (float*)carve((size_t)N_NODES * 4 * 4);
    float* ADST   = (float*)carve((size_t)N_NODES * 4 * 4);
    float* B      = (float*)carve((size_t)N_NODES * 128 * 4);

    const int* esrc = ei;
    const int* edst = ei + N_EDGES;

    hipMemsetAsync(cnt, 0, (size_t)N_NODES * 4, stream);
    int egrid = (E_TOT + 255) / 256;
    count_deg<<<egrid, 256, 0, stream>>>(edst, cnt);
    scan_block<<<1, 1024, 0, stream>>>(cnt, offs);
    hipMemcpyAsync(cursor, offs, (size_t)N_NODES * 4, hipMemcpyDeviceToDevice, stream);
    scatter_edges<<<egrid, 256, 0, stream>>>(esrc, edst, cursor, csr);

    int agrid = (N_NODES * HEADS + 255) / 256;
    int ngrid = N_NODES / 4;

    // ---- layer 1 ----
    {
        dim3 g((128 + 63) / 64, (N_NODES + 63) / 64);
        gemm_xwt<<<g, 256, 0, stream>>>(x, W1, nullptr, HF, HFb, N_NODES, 100, 128);
        gemm_xwt<<<g, 256, 0, stream>>>(x, Wl1, bl1, LIN, nullptr, N_NODES, 100, 128);
        calc_alpha<<<agrid, 256, 0, stream>>>(HF, a1s, a1d, ASRC, ADST, 32, 128);
        agg12<<<ngrid, 256, 0, stream>>>(offs, csr, (const unsigned*)HFb, ASRC, ADST, b1, LIN, B);
    }
    // ---- layer 2 ----
    {
        dim3 g((128 + 63) / 64, (N_NODES + 63) / 64);
        gemm_xwt<<<g, 256, 0, stream>>>(B, W2, nullptr, HF, HFb, N_NODES, 128, 128);
        gemm_xwt<<<g, 256, 0, stream>>>(B, Wl2, bl2, LIN, nullptr, N_NODES, 128, 128);
        calc_alpha<<<agrid, 256, 0, stream>>>(HF, a2s, a2d, ASRC, ADST, 32, 128);
        agg12<<<ngrid, 256, 0, stream>>>(offs, csr, (const unsigned*)HFb, ASRC, ADST, b2, LIN, B);
    }
    // ---- layer 3 ----
    {
        dim3 g3a((188 + 63) / 64, (N_NODES + 63) / 64);
        gemm_xwt<<<g3a, 256, 0, stream>>>(B, W3, nullptr, HF, HFb, N_NODES, 128, 188);
        dim3 g3b((47 + 63) / 64, (N_NODES + 63) / 64);
        gemm_xwt<<<g3b, 256, 0, stream>>>(B, Wl3, bl3, LIN, nullptr, N_NODES, 128, 47);
        calc_alpha<<<agrid, 256, 0, stream>>>(HF, a3s, a3d, ASRC, ADST, 47, 188);
        agg3<<<ngrid, 256, 0, stream>>>(offs, csr, (const unsigned*)HFb, ASRC, ADST, b3, LIN, out);
    }
}